// Round 6
// baseline (57257.355 us; speedup 1.0000x reference)
//
#include <hip/hip_runtime.h>
#include <hip/hip_cooperative_groups.h>

namespace cg = cooperative_groups;

#define VOCAB 50257
#define EMBED 512
#define HIDDEN 1024
#define SEQLEN 512
#define XDIM 1024      // 2*EMBED
#define NG 6283        // ceil(VOCAB/8) 8-row groups
#define NGP 25         // ceil(NG/256) per-thread slots
#define CANDG 64       // candidate group cap
#define CANDR 256      // candidate row cap

typedef unsigned long long u64;
typedef unsigned int u32;
typedef unsigned short u16;

// monotone mapping float -> u32 (order-preserving for all finite floats)
__device__ __forceinline__ u32 fmono(float f) {
  u32 b = __float_as_uint(f);
  return b ^ ((b & 0x80000000u) ? 0xFFFFFFFFu : 0x80000000u);
}
__device__ __forceinline__ float funmono(u32 v) {
  u32 b = (v & 0x80000000u) ? (v ^ 0x80000000u) : ~v;
  return __uint_as_float(b);
}

__device__ __forceinline__ float wave_reduce_sum(float v) {
#pragma unroll
  for (int off = 32; off > 0; off >>= 1) v += __shfl_down(v, off);
  return v;
}

__device__ __forceinline__ u64 wave_reduce_max_u64(u64 v) {
#pragma unroll
  for (int off = 32; off > 0; off >>= 1) {
    u64 o = __shfl_down(v, off);
    if (o > v) v = o;
  }
  return v;
}

// fp32 -> bf16 round-to-nearest-even (finite inputs only)
__device__ __forceinline__ u16 f2bf_rne(float f) {
  u32 u = __float_as_uint(f);
  u32 r = (u + 0x7FFFu + ((u >> 16) & 1u)) >> 16;
  return (u16)r;
}

// dot of 8 bf16 (packed in uint4) with 8 fp32 (two float4)
__device__ __forceinline__ float dot8(uint4 w, float4 hx, float4 hy) {
  float a = 0.f;
  u32 u;
  u = w.x; a += __uint_as_float(u << 16) * hx.x + __uint_as_float(u & 0xFFFF0000u) * hx.y;
  u = w.y; a += __uint_as_float(u << 16) * hx.z + __uint_as_float(u & 0xFFFF0000u) * hx.w;
  u = w.z; a += __uint_as_float(u << 16) * hy.x + __uint_as_float(u & 0xFFFF0000u) * hy.y;
  u = w.w; a += __uint_as_float(u << 16) * hy.z + __uint_as_float(u & 0xFFFF0000u) * hy.w;
  return a;
}

// ===================== fused persistent kernel =====================
// One cooperative launch runs: bf16 weight convert, h/c init, all 512
// steps (refine -> LSTM gates -> grid.sync -> bf16 screen -> grid.sync),
// and the final exact fp32 logits. All arithmetic on values that feed the
// token trajectory is bit-identical to the round-5 kernels.
__global__ __launch_bounds__(256, 2)
void fused_all(const int* __restrict__ seq,
               const float* __restrict__ emb,
               const float* __restrict__ wih, const float* __restrict__ whh,
               const float* __restrict__ bih, const float* __restrict__ bhh,
               const float* __restrict__ wlin, const float* __restrict__ blin,
               const float* __restrict__ h0, const float* __restrict__ c0,
               u16* __restrict__ wb, float* __restrict__ hbufs,
               float* __restrict__ cbufs, float* __restrict__ Lb,
               u64* __restrict__ gslots, float* __restrict__ out) {
  cg::grid_group grid = cg::this_grid();

  const int tid = threadIdx.x;
  const int lane = tid & 63;
  const int wid = tid >> 6;
  const int bid = blockIdx.x;
  const int G = gridDim.x;
  const int nthreads = G << 8;
  const int gtid = (bid << 8) + tid;
  const int nw = G << 2;            // total waves
  const int gw = (bid << 2) + wid;  // global wave id
  const int UPB = HIDDEN / G;       // hidden units per block (2 at G=512)

  __shared__ __align__(16) float xs[XDIM];
  __shared__ __align__(16) float hs[HIDDEN];
  __shared__ float sred[4];
  __shared__ u64 mred[4];
  __shared__ u64 bred[4];
  __shared__ float gl[16];          // gates: [UPB<=4][4]
  __shared__ int listg[CANDG];
  __shared__ int listr[CANDR];
  __shared__ int cntg, cntr, ptokS;

  // ---- phase 0: convert W_lin -> bf16 (grid-strided); init h/c ----
  {
    const long long n8 = (long long)VOCAB * HIDDEN / 8;
    const float4* src = (const float4*)wlin;
    for (long long i8 = gtid; i8 < n8; i8 += nthreads) {
      const float4 a = src[2 * i8];
      const float4 b = src[2 * i8 + 1];
      uint4 o;
      o.x = (u32)f2bf_rne(a.x) | ((u32)f2bf_rne(a.y) << 16);
      o.y = (u32)f2bf_rne(a.z) | ((u32)f2bf_rne(a.w) << 16);
      o.z = (u32)f2bf_rne(b.x) | ((u32)f2bf_rne(b.y) << 16);
      o.w = (u32)f2bf_rne(b.z) | ((u32)f2bf_rne(b.w) << 16);
      ((uint4*)wb)[i8] = o;
    }
    if (bid == 0) {
      for (int i = tid; i < HIDDEN; i += 256) {
        hbufs[i] = h0[i];
        cbufs[i] = c0[i];
      }
    }
  }
  grid.sync();

  for (int t = 0; t < SEQLEN; ++t) {
    const float* hin = hbufs + (t & 1) * HIDDEN;
    const float* cin = cbufs + (t & 1) * HIDDEN;
    float* hout = hbufs + ((t + 1) & 1) * HIDDEN;
    float* cout = cbufs + ((t + 1) & 1) * HIDDEN;

    // stage h(t); fold sum|h| in the same pass
    float s = 0.f;
    for (int i = tid; i < HIDDEN; i += 256) {
      const float hv = hin[i];
      hs[i] = hv;
      s += fabsf(hv);
    }

    int ptok = 0;
    if (t > 0) {
      // ---- refine of step t-1's argmax (redundant per block, cheap) ----
      // pass 1: global max over NG group slots (static unroll, registers)
      u64 v = 0;
#pragma unroll
      for (int k = 0; k < NGP; ++k) {
        const int i = tid + (k << 8);
        if (i < NG) {
          const u64 p = gslots[i];
          if (p > v) v = p;
        }
      }
      v = wave_reduce_max_u64(v);
      s = wave_reduce_sum(s);
      if (lane == 0) {
        mred[wid] = v;
        sred[wid] = s;
      }
      if (tid == 0) { cntg = 0; cntr = 0; }
      __syncthreads();
      u64 m = mred[0];
      if (mred[1] > m) m = mred[1];
      if (mred[2] > m) m = mred[2];
      if (mred[3] > m) m = mred[3];
      const float S = sred[0] + sred[1] + sred[2] + sred[3];
      const float maxb = funmono((u32)(m >> 32));
      // |L_bf16 - L_fp32| <= S*(1/32)*2^-9 per side (RNE), + order margin
      const float thr = maxb - 2.0f * (S * 6.1035156e-5f) - 2e-3f;

      // pass 2: candidate groups (reload, L2-hot)
#pragma unroll
      for (int k = 0; k < NGP; ++k) {
        const int i = tid + (k << 8);
        if (i < NG && funmono((u32)(gslots[i] >> 32)) >= thr) {
          int ix = atomicAdd(&cntg, 1);
          if (ix < CANDG) listg[ix] = i;
        }
      }
      __syncthreads();
      const int ngc = (cntg < CANDG) ? cntg : CANDG;

      // candidate rows within candidate groups
      for (int idx = tid; idx < ngc * 8; idx += 256) {
        const int row = listg[idx >> 3] * 8 + (idx & 7);
        if (row < VOCAB && Lb[row] >= thr) {
          int ix = atomicAdd(&cntr, 1);
          if (ix < CANDR) listr[ix] = row;
        }
      }
      __syncthreads();
      const int nr = (cntr < CANDR) ? cntr : CANDR;

      // exact fp32 recompute of candidate rows (round-0 dot order)
      u64 best = 0;
      for (int ci = wid; ci < nr; ci += 4) {
        const int row = listr[ci];
        const float4* wr = (const float4*)(wlin + (size_t)row * HIDDEN);
        float a = 0.f;
#pragma unroll
        for (int i = 0; i < 4; ++i) {
          const int k = lane + i * 64;
          const float4 w4 = wr[k];
          const float4 h4 = *((const float4*)&hs[k * 4]);
          a += w4.x * h4.x + w4.y * h4.y + w4.z * h4.z + w4.w * h4.w;
        }
        a = wave_reduce_sum(a);
        if (lane == 0) {
          const u64 pk = ((u64)fmono(a + blin[row]) << 32) | (u32)(VOCAB - row);
          if (pk > best) best = pk;
        }
      }
      if (lane == 0) bred[wid] = best;
      __syncthreads();
      if (tid == 0) {
        u64 b = bred[0];
        if (bred[1] > b) b = bred[1];
        if (bred[2] > b) b = bred[2];
        if (bred[3] > b) b = bred[3];
        ptokS = VOCAB - (int)(u32)(b & 0xFFFFFFFFu);
      }
      __syncthreads();
      ptok = ptokS;
    }

    // stage x = [prev_embed, tok_embed]
    const int tok = seq[t];
    for (int i = tid; i < EMBED; i += 256) {
      xs[i] = (t == 0) ? 0.0f : emb[(size_t)ptok * EMBED + i];
      xs[EMBED + i] = emb[(size_t)tok * EMBED + i];
    }
    __syncthreads();

    // ---- phase A: gates for this block's UPB hidden units ----
    for (int u = 0; u < UPB; ++u) {
      const int j = bid * UPB + u;
      const float4* wx = (const float4*)(wih + (size_t)(wid * HIDDEN + j) * XDIM);
      const float4* wh = (const float4*)(whh + (size_t)(wid * HIDDEN + j) * HIDDEN);
      float a = 0.f;
#pragma unroll
      for (int i = 0; i < 4; ++i) {
        const int k = lane + i * 64;
        const float4 w4 = wx[k];
        const float4 x4 = *((const float4*)&xs[k * 4]);
        a += w4.x * x4.x + w4.y * x4.y + w4.z * x4.z + w4.w * x4.w;
        const float4 v4 = wh[k];
        const float4 h4 = *((const float4*)&hs[k * 4]);
        a += v4.x * h4.x + v4.y * h4.y + v4.z * h4.z + v4.w * h4.w;
      }
      a = wave_reduce_sum(a);
      if (lane == 0) gl[u * 4 + wid] = a;
    }
    __syncthreads();
    if (tid < UPB) {
      const int j = bid * UPB + tid;
      const float gi = gl[tid * 4 + 0] + bih[j] + bhh[j];
      const float gf = gl[tid * 4 + 1] + bih[HIDDEN + j] + bhh[HIDDEN + j];
      const float gg = gl[tid * 4 + 2] + bih[2 * HIDDEN + j] + bhh[2 * HIDDEN + j];
      const float go = gl[tid * 4 + 3] + bih[3 * HIDDEN + j] + bhh[3 * HIDDEN + j];
      const float si = 1.0f / (1.0f + expf(-gi));
      const float sf = 1.0f / (1.0f + expf(-gf));
      const float tg = tanhf(gg);
      const float so = 1.0f / (1.0f + expf(-go));
      const float c2 = sf * cin[j] + si * tg;
      const float h2 = so * tanhf(c2);
      cout[j] = c2;
      hout[j] = h2;
    }
    grid.sync();  // h(t+1) visible grid-wide

    // ---- phase B: bf16 screen of h(t+1) (skip on the last step) ----
    if (t < SEQLEN - 1) {
      const float4* h4p = (const float4*)hout;
      const float4 ha0 = h4p[2 * lane];
      const float4 ha1 = h4p[2 * lane + 1];
      const float4 hb0 = h4p[2 * (lane + 64)];
      const float4 hb1 = h4p[2 * (lane + 64) + 1];

      const uint4 z4 = make_uint4(0u, 0u, 0u, 0u);
      for (int grp = gw; grp < NG; grp += nw) {
        const int row0 = grp * 8;
        float acc[8];
        uint4 w0[4], w1[4];
        // rows 0..3: stage then compute (ILP)
#pragma unroll
        for (int r = 0; r < 4; ++r) {
          const int row = row0 + r;
          const uint4* wr = (const uint4*)(wb + (size_t)row * HIDDEN);
          const bool ok = row < VOCAB;
          w0[r] = ok ? wr[lane] : z4;
          w1[r] = ok ? wr[lane + 64] : z4;
        }
#pragma unroll
        for (int r = 0; r < 4; ++r)
          acc[r] = dot8(w0[r], ha0, ha1) + dot8(w1[r], hb0, hb1);
        // rows 4..7
#pragma unroll
        for (int r = 0; r < 4; ++r) {
          const int row = row0 + 4 + r;
          const uint4* wr = (const uint4*)(wb + (size_t)row * HIDDEN);
          const bool ok = row < VOCAB;
          w0[r] = ok ? wr[lane] : z4;
          w1[r] = ok ? wr[lane + 64] : z4;
        }
#pragma unroll
        for (int r = 0; r < 4; ++r)
          acc[4 + r] = dot8(w0[r], ha0, ha1) + dot8(w1[r], hb0, hb1);

#pragma unroll
        for (int off = 32; off > 0; off >>= 1) {
#pragma unroll
          for (int r = 0; r < 8; ++r) acc[r] += __shfl_down(acc[r], off);
        }

        if (lane == 0) {
          u64 best = 0;
#pragma unroll
          for (int r = 0; r < 8; ++r) {
            const int row = row0 + r;
            if (row < VOCAB) {
              const float lg = acc[r] + blin[row];
              Lb[row] = lg;
              const u64 pk = ((u64)fmono(lg) << 32) | (u32)(VOCAB - row);
              if (pk > best) best = pk;
            }
          }
          gslots[grp] = best;  // own slot, plain store
        }
      }
      grid.sync();  // Lb + gslots visible for next step's refine
    }
  }

  // ---- final exact fp32 logits of step 511 -> out (round-0 dot order) ----
  {
    for (int i = tid; i < HIDDEN; i += 256) hs[i] = hbufs[i];  // parity 0
    __syncthreads();
    for (int row = gw; row < VOCAB; row += nw) {
      const float4* wr = (const float4*)(wlin + (size_t)row * HIDDEN);
      float a = 0.f;
#pragma unroll
      for (int i = 0; i < 4; ++i) {
        const int k = lane + i * 64;
        const float4 w4 = wr[k];
        const float4 h4 = *((const float4*)&hs[k * 4]);
        a += w4.x * h4.x + w4.y * h4.y + w4.z * h4.z + w4.w * h4.w;
      }
      a = wave_reduce_sum(a);
      if (lane == 0) out[row] = a + blin[row];
    }
  }
}

// ====================== fallback (round-0) path ======================

__global__ void init_state_v0(const float* __restrict__ h0, const float* __restrict__ c0,
                              float* __restrict__ hbufs, float* __restrict__ cbufs,
                              u64* __restrict__ partials) {
  int i = threadIdx.x;
  if (i < HIDDEN) {
    hbufs[i] = h0[i];
    cbufs[i] = c0[i];
  }
  if (i < 512) partials[i] = 0ull;
}

__global__ __launch_bounds__(256)
void lstm_step_v0(const float* __restrict__ emb,
                  const float* __restrict__ wih, const float* __restrict__ whh,
                  const float* __restrict__ bih, const float* __restrict__ bhh,
                  const int* __restrict__ seq,
                  float* __restrict__ hbufs, float* __restrict__ cbufs,
                  u64* __restrict__ partials, int t) {
  __shared__ __align__(16) float xs[XDIM];
  __shared__ __align__(16) float hs[HIDDEN];
  __shared__ u64 red[4];
  __shared__ int ptok_s;

  const int tid = threadIdx.x;
  const int lane = tid & 63;
  const int wid = tid >> 6;

  const float* hin = hbufs + (t & 1) * HIDDEN;
  const float* cin = cbufs + (t & 1) * HIDDEN;
  float* hout = hbufs + ((t + 1) & 1) * HIDDEN;
  float* cout = cbufs + ((t + 1) & 1) * HIDDEN;

  int ptok = -1;
  if (t > 0) {
    const u64* part = partials + ((t + 1) & 1) * 256;
    u64 v = wave_reduce_max_u64(part[tid]);
    if (lane == 0) red[wid] = v;
    __syncthreads();
    if (tid == 0) {
      u64 m = red[0];
      if (red[1] > m) m = red[1];
      if (red[2] > m) m = red[2];
      if (red[3] > m) m = red[3];
      ptok_s = VOCAB - (int)(u32)(m & 0xFFFFFFFFu);
    }
    __syncthreads();
    ptok = ptok_s;
  }
  if (blockIdx.x == 0) partials[(t & 1) * 256 + tid] = 0ull;

  const int tok = seq[t];
  for (int i = tid; i < EMBED; i += 256) {
    xs[i] = (t == 0) ? 0.0f : emb[(size_t)ptok * EMBED + i];
    xs[EMBED + i] = emb[(size_t)tok * EMBED + i];
  }
  for (int i = tid; i < HIDDEN; i += 256) hs[i] = hin[i];
  __syncthreads();

  const int j = blockIdx.x * 4 + wid;
  float acc[4];
#pragma unroll
  for (int g = 0; g < 4; ++g) {
    const float4* wx = (const float4*)(wih + (size_t)(g * HIDDEN + j) * XDIM);
    const float4* wh = (const float4*)(whh + (size_t)(g * HIDDEN + j) * HIDDEN);
    float a = 0.f;
#pragma unroll
    for (int i = 0; i < 4; ++i) {
      const int k = lane + i * 64;
      float4 w4 = wx[k];
      float4 x4 = *((const float4*)&xs[k * 4]);
      a += w4.x * x4.x + w4.y * x4.y + w4.z * x4.z + w4.w * x4.w;
      float4 v4 = wh[k];
      float4 h4 = *((const float4*)&hs[k * 4]);
      a += v4.x * h4.x + v4.y * h4.y + v4.z * h4.z + v4.w * h4.w;
    }
    acc[g] = wave_reduce_sum(a);
  }

  if (lane == 0) {
    float gi = acc[0] + bih[j] + bhh[j];
    float gf = acc[1] + bih[HIDDEN + j] + bhh[HIDDEN + j];
    float gg = acc[2] + bih[2 * HIDDEN + j] + bhh[2 * HIDDEN + j];
    float go = acc[3] + bih[3 * HIDDEN + j] + bhh[3 * HIDDEN + j];
    float si = 1.0f / (1.0f + expf(-gi));
    float sf = 1.0f / (1.0f + expf(-gf));
    float tg = tanhf(gg);
    float so = 1.0f / (1.0f + expf(-go));
    float c2 = sf * cin[j] + si * tg;
    float h2 = so * tanhf(c2);
    cout[j] = c2;
    hout[j] = h2;
  }
}

__global__ __launch_bounds__(256)
void logits_step_v0(const float* __restrict__ wlin, const float* __restrict__ blin,
                    const float* __restrict__ hbufs, float* __restrict__ out,
                    u64* __restrict__ partials, int t) {
  __shared__ __align__(16) float hs[HIDDEN];
  __shared__ u64 red[4];
  const int tid = threadIdx.x;
  const int lane = tid & 63;
  const int wid = tid >> 6;

  const float* h = hbufs + ((t + 1) & 1) * HIDDEN;
  for (int i = tid; i < HIDDEN; i += 256) hs[i] = h[i];
  __syncthreads();

  const int row = blockIdx.x * 4 + wid;
  u64 pk = 0ull;
  if (row < VOCAB) {
    const float4* wr = (const float4*)(wlin + (size_t)row * HIDDEN);
    float a = 0.f;
#pragma unroll
    for (int i = 0; i < 4; ++i) {
      const int k = lane + i * 64;
      float4 w4 = wr[k];
      float4 h4 = *((const float4*)&hs[k * 4]);
      a += w4.x * h4.x + w4.y * h4.y + w4.z * h4.z + w4.w * h4.w;
    }
    a = wave_reduce_sum(a);
    if (lane == 0) {
      float logit = a + blin[row];
      out[row] = logit;
      pk = ((u64)fmono(logit) << 32) | (u32)(VOCAB - row);
    }
  }
  if (lane == 0) red[wid] = pk;
  __syncthreads();
  if (tid == 0) {
    u64 m = red[0];
    if (red[1] > m) m = red[1];
    if (red[2] > m) m = red[2];
    if (red[3] > m) m = red[3];
    atomicMax(&partials[(t & 1) * 256 + (blockIdx.x & 255)], m);
  }
}

extern "C" void kernel_launch(void* const* d_in, const int* in_sizes, int n_in,
                              void* d_out, int out_size, void* d_ws, size_t ws_size,
                              hipStream_t stream) {
  const int* seq = (const int*)d_in[0];
  const float* h0 = (const float*)d_in[1];
  const float* c0 = (const float*)d_in[2];
  const float* emb = (const float*)d_in[3];
  const float* wih = (const float*)d_in[4];
  const float* whh = (const float*)d_in[5];
  const float* bih = (const float*)d_in[6];
  const float* bhh = (const float*)d_in[7];
  const float* wlin = (const float*)d_in[8];
  const float* blin = (const float*)d_in[9];
  float* out = (float*)d_out;

  // ws layout (16B-aligned offsets)
  const size_t OFF_G = 0;                    // gslots: NG u64 (50264B, pad)
  const size_t OFF_H = 51200;                // hbufs: 2*1024 f
  const size_t OFF_C = OFF_H + 8192;         // cbufs: 2*1024 f
  const size_t OFF_LB = OFF_C + 8192;        // Lb: NG*8 floats (201056B, pad)
  const size_t OFF_WB = OFF_LB + 201216;     // wb: VOCAB*HIDDEN bf16
  const size_t NEED = OFF_WB + (size_t)VOCAB * HIDDEN * 2;

  u64* gslots = (u64*)((char*)d_ws + OFF_G);
  float* hbufs = (float*)((char*)d_ws + OFF_H);
  float* cbufs = (float*)((char*)d_ws + OFF_C);
  float* Lb = (float*)((char*)d_ws + OFF_LB);
  u16* wb = (u16*)((char*)d_ws + OFF_WB);

  bool coop_ok = (ws_size >= NEED);
  int G = 512;
  if (coop_ok) {
    int maxb = 0;
    hipError_t e = hipOccupancyMaxActiveBlocksPerMultiprocessor(&maxb, fused_all, 256, 0);
    if (e != hipSuccess || maxb < 1) coop_ok = false;
    else if (maxb < 2) G = 256;  // 1 block/CU still co-resident on 256 CUs
  }

  if (coop_ok) {
    const int* a_seq = seq;
    const float* a_emb = emb;
    const float* a_wih = wih;
    const float* a_whh = whh;
    const float* a_bih = bih;
    const float* a_bhh = bhh;
    const float* a_wlin = wlin;
    const float* a_blin = blin;
    const float* a_h0 = h0;
    const float* a_c0 = c0;
    u16* a_wb = wb;
    float* a_hb = hbufs;
    float* a_cb = cbufs;
    float* a_lb = Lb;
    u64* a_gs = gslots;
    float* a_out = out;
    void* args[] = {&a_seq, &a_emb, &a_wih, &a_whh, &a_bih, &a_bhh,
                    &a_wlin, &a_blin, &a_h0, &a_c0, &a_wb, &a_hb,
                    &a_cb, &a_lb, &a_gs, &a_out};
    hipLaunchCooperativeKernel((void*)fused_all, dim3(G), dim3(256), args, 0, stream);
  } else {
    // fallback: round-0 fp32 path (known-correct)
    u64* p0 = (u64*)d_ws;
    float* hb0 = (float*)((char*)d_ws + 4096);
    float* cb0 = hb0 + 2 * HIDDEN;
    init_state_v0<<<1, 1024, 0, stream>>>(h0, c0, hb0, cb0, p0);
    for (int t = 0; t < SEQLEN; ++t) {
      lstm_step_v0<<<HIDDEN / 4, 256, 0, stream>>>(emb, wih, whh, bih, bhh, seq,
                                                   hb0, cb0, p0, t);
      logits_step_v0<<<(VOCAB + 3) / 4, 256, 0, stream>>>(wlin, blin, hb0, out,
                                                          p0, t);
    }
  }
}

// Round 7
// 20794.292 us; speedup vs baseline: 2.7535x; 2.7535x over previous
//
#include <hip/hip_runtime.h>

#define VOCAB 50257
#define EMBED 512
#define HIDDEN 1024
#define SEQLEN 512
#define XDIM 1024   // 2*EMBED
#define NSB 1571    // ceil(VOCAB/32): screen blocks / per-block max slots
#define NGB 1024    // gate blocks in screen_gp (4096 rows / 4 waves)
#define CANDB 128   // candidate-block cap
#define CANDR 512   // candidate-row cap

typedef unsigned long long u64;
typedef unsigned int u32;
typedef unsigned short u16;

// monotone mapping float -> u32 (order-preserving for all finite floats)
__device__ __forceinline__ u32 fmono(float f) {
  u32 b = __float_as_uint(f);
  return b ^ ((b & 0x80000000u) ? 0xFFFFFFFFu : 0x80000000u);
}
// inverse of fmono
__device__ __forceinline__ float funmono(u32 v) {
  u32 b = (v & 0x80000000u) ? (v ^ 0x80000000u) : ~v;
  return __uint_as_float(b);
}

__device__ __forceinline__ float wave_reduce_sum(float v) {
#pragma unroll
  for (int off = 32; off > 0; off >>= 1) v += __shfl_down(v, off);
  return v;
}

__device__ __forceinline__ u64 wave_reduce_max_u64(u64 v) {
#pragma unroll
  for (int off = 32; off > 0; off >>= 1) {
    u64 o = __shfl_down(v, off);
    if (o > v) v = o;
  }
  return v;
}

// fp32 -> bf16 round-to-nearest-even (finite inputs only)
__device__ __forceinline__ u16 f2bf_rne(float f) {
  u32 u = __float_as_uint(f);
  u32 r = (u + 0x7FFFu + ((u >> 16) & 1u)) >> 16;
  return (u16)r;
}

// dot of 8 bf16 (packed in uint4) with 8 fp32 (two float4)
__device__ __forceinline__ float dot8(uint4 w, float4 hx, float4 hy) {
  float a = 0.f;
  u32 u;
  u = w.x; a += __uint_as_float(u << 16) * hx.x + __uint_as_float(u & 0xFFFF0000u) * hx.y;
  u = w.y; a += __uint_as_float(u << 16) * hx.z + __uint_as_float(u & 0xFFFF0000u) * hx.w;
  u = w.z; a += __uint_as_float(u << 16) * hy.x + __uint_as_float(u & 0xFFFF0000u) * hy.y;
  u = w.w; a += __uint_as_float(u << 16) * hy.z + __uint_as_float(u & 0xFFFF0000u) * hy.w;
  return a;
}

__device__ __forceinline__ float dotf4(float4 a, float4 b) {
  return a.x * b.x + a.y * b.y + a.z * b.z + a.w * b.w;
}

// ============================ setup kernels ============================

__global__ void init_state(const float* __restrict__ h0, const float* __restrict__ c0,
                           float* __restrict__ hbufs, float* __restrict__ cbufs) {
  int i = threadIdx.x;
  if (i < HIDDEN) {
    hbufs[i] = h0[i];
    cbufs[i] = c0[i];
  }
}

// one-shot fp32 -> bf16 conversion of W_lin into workspace
__global__ __launch_bounds__(256)
void convert_wlin(const float* __restrict__ wlin, u16* __restrict__ wb) {
  const long long i8 = (long long)blockIdx.x * 256 + threadIdx.x;  // group of 8 floats
  const long long n8 = (long long)VOCAB * HIDDEN / 8;
  if (i8 >= n8) return;
  const float4* src = (const float4*)wlin;
  float4 a = src[2 * i8];
  float4 b = src[2 * i8 + 1];
  uint4 o;
  o.x = (u32)f2bf_rne(a.x) | ((u32)f2bf_rne(a.y) << 16);
  o.y = (u32)f2bf_rne(a.z) | ((u32)f2bf_rne(a.w) << 16);
  o.z = (u32)f2bf_rne(b.x) | ((u32)f2bf_rne(b.y) << 16);
  o.w = (u32)f2bf_rne(b.z) | ((u32)f2bf_rne(b.w) << 16);
  ((uint4*)wb)[i8] = o;
}

// gp(0): gp[row] = bih[row]+bhh[row] + wihR[row]·emb[seq[0]] + whh[row]·h0
// grid NGB x 256; wave -> row = (bid<<2)+wid
__global__ __launch_bounds__(256)
void gates_init(const float* __restrict__ wih, const float* __restrict__ whh,
                const float* __restrict__ bih, const float* __restrict__ bhh,
                const float* __restrict__ emb, const int* __restrict__ seq,
                const float* __restrict__ hbufs, float* __restrict__ gp) {
  __shared__ __align__(16) float xs2[EMBED];
  __shared__ __align__(16) float hs2[HIDDEN];
  const int tid = threadIdx.x;
  const int lane = tid & 63;
  const int wid = tid >> 6;
  const int tok = seq[0];
  for (int i = tid; i < EMBED; i += 256) xs2[i] = emb[(size_t)tok * EMBED + i];
  for (int i = tid; i < HIDDEN; i += 256) hs2[i] = hbufs[i];  // h0 at parity 0
  __syncthreads();

  const int row = (blockIdx.x << 2) + wid;
  const float4* wr = (const float4*)(wih + (size_t)row * XDIM);  // 256 float4s
  const float4* hr = (const float4*)(whh + (size_t)row * HIDDEN);
  float a = 0.f;
#pragma unroll
  for (int i = 0; i < 2; ++i) {
    const int k = lane + i * 64;
    a += dotf4(wr[128 + k], *((const float4*)&xs2[k * 4]));  // cols 512..1023
  }
#pragma unroll
  for (int i = 0; i < 4; ++i) {
    const int k = lane + i * 64;
    a += dotf4(hr[k], *((const float4*)&hs2[k * 4]));
  }
  a = wave_reduce_sum(a);
  if (lane == 0) gp[row] = a + bih[row] + bhh[row];
}

// ============================ fast path ============================

// A (thin): refine of step t-1's screen (round-5 numerics, unchanged) ->
// ptok; gates = gp[row] + wihL[row]·emb[ptok]; pointwise -> h(t+1), c(t+1).
// 256 blocks x 256 threads; wave -> unit j = (bid<<2)+wid.
__global__ __launch_bounds__(256)
void lstm_thin(const float* __restrict__ emb, const float* __restrict__ wih,
               const float* __restrict__ wlin, const float* __restrict__ blin,
               const float* __restrict__ gp,
               float* __restrict__ hbufs, float* __restrict__ cbufs,
               const u64* __restrict__ partials, const float* __restrict__ Lb,
               int t) {
  __shared__ __align__(16) float xs[EMBED];
  __shared__ __align__(16) float hs[HIDDEN];
  __shared__ float sred[4];
  __shared__ u64 mred[4];
  __shared__ u64 bred[4];
  __shared__ int listb[CANDB];
  __shared__ int listr[CANDR];
  __shared__ int cntb, cntr;
  __shared__ int ptokS;

  const int tid = threadIdx.x;
  const int lane = tid & 63;
  const int wid = tid >> 6;

  const float* hin = hbufs + (t & 1) * HIDDEN;
  const float* cin = cbufs + (t & 1) * HIDDEN;
  float* hout = hbufs + ((t + 1) & 1) * HIDDEN;
  float* cout = cbufs + ((t + 1) & 1) * HIDDEN;

  const u64* part = partials + ((t + 1) & 1) * NSB;  // parity (t-1)&1

  // pass 1: global max of screen-block maxima (static unroll -> pure regs)
  u64 v = 0;
  if (t > 0) {
#pragma unroll
    for (int k = 0; k < 7; ++k) {
      const int i = tid + (k << 8);
      if (i < NSB) {
        const u64 p = part[i];
        if (p > v) v = p;
      }
    }
  }

  // stage h(t); fold |h| sum in the same pass
  float s = 0.f;
  for (int i = tid; i < HIDDEN; i += 256) {
    const float hv = hin[i];
    hs[i] = hv;
    s += fabsf(hv);
  }

  int ptok = 0;
  if (t > 0) {
    v = wave_reduce_max_u64(v);
    s = wave_reduce_sum(s);
    if (lane == 0) {
      mred[wid] = v;
      sred[wid] = s;
    }
    if (tid == 0) { cntb = 0; cntr = 0; }
    __syncthreads();

    u64 m = mred[0];
    if (mred[1] > m) m = mred[1];
    if (mred[2] > m) m = mred[2];
    if (mred[3] > m) m = mred[3];
    const float S = sred[0] + sred[1] + sred[2] + sred[3];
    const float maxb = funmono((u32)(m >> 32));
    // |L_bf16 - L_fp32| <= S*(1/32)*2^-9 per side (RNE), + fp32-order margin
    const float thr = maxb - 2.0f * (S * 6.1035156e-5f) - 2e-3f;

    // pass 2: candidate blocks (reload; L2-hot after pass 1)
#pragma unroll
    for (int k = 0; k < 7; ++k) {
      const int i = tid + (k << 8);
      if (i < NSB && funmono((u32)(part[i] >> 32)) >= thr) {
        int ix = atomicAdd(&cntb, 1);
        if (ix < CANDB) listb[ix] = i;
      }
    }
    __syncthreads();
    const int nb = (cntb < CANDB) ? cntb : CANDB;

    // scan candidate blocks' Lb segments for candidate rows
    for (int idx = tid; idx < nb * 32; idx += 256) {
      const int row = listb[idx >> 5] * 32 + (idx & 31);
      if (row < VOCAB && Lb[row] >= thr) {
        int ix = atomicAdd(&cntr, 1);
        if (ix < CANDR) listr[ix] = row;
      }
    }
    __syncthreads();
    const int nr = (cntr < CANDR) ? cntr : CANDR;

    // exact fp32 recompute of candidate rows, one wave per row
    u64 best = 0;
    for (int ci = wid; ci < nr; ci += 4) {
      const int row = listr[ci];
      const float4* wr = (const float4*)(wlin + (size_t)row * HIDDEN);
      float a = 0.f;
#pragma unroll
      for (int i = 0; i < 4; ++i) {
        const int k = lane + i * 64;
        a += dotf4(wr[k], *((const float4*)&hs[k * 4]));
      }
      a = wave_reduce_sum(a);
      if (lane == 0) {
        const u64 pk = ((u64)fmono(a + blin[row]) << 32) | (u32)(VOCAB - row);
        if (pk > best) best = pk;
      }
    }
    if (lane == 0) bred[wid] = best;
    __syncthreads();
    if (tid == 0) {
      u64 b = bred[0];
      if (bred[1] > b) b = bred[1];
      if (bred[2] > b) b = bred[2];
      if (bred[3] > b) b = bred[3];
      ptokS = VOCAB - (int)(u32)(b & 0xFFFFFFFFu);
    }
    __syncthreads();
    ptok = ptokS;
  }

  // stage x_prev = emb[ptok] (zeros at t=0 handled by skipping the dot)
  if (t > 0) {
    for (int i = tid; i < EMBED; i += 256) xs[i] = emb[(size_t)ptok * EMBED + i];
  }
  __syncthreads();

  // gates: unit j, rows {j, j+H, j+2H, j+3H} of wihL (cols 0..511)
  const int j = (blockIdx.x << 2) + wid;
  float ag[4] = {0.f, 0.f, 0.f, 0.f};
  if (t > 0) {
    const float4 xv0 = *((const float4*)&xs[lane * 4]);
    const float4 xv1 = *((const float4*)&xs[(lane + 64) * 4]);
    float4 wv[8];
#pragma unroll
    for (int g = 0; g < 4; ++g) {
      const float4* wr = (const float4*)(wih + (size_t)(g * HIDDEN + j) * XDIM);
      wv[2 * g] = wr[lane];
      wv[2 * g + 1] = wr[lane + 64];
    }
#pragma unroll
    for (int g = 0; g < 4; ++g)
      ag[g] = dotf4(wv[2 * g], xv0) + dotf4(wv[2 * g + 1], xv1);
#pragma unroll
    for (int off = 32; off > 0; off >>= 1) {
#pragma unroll
      for (int g = 0; g < 4; ++g) ag[g] += __shfl_down(ag[g], off);
    }
  }

  if (lane == 0) {
    const float gi = gp[j] + ag[0];
    const float gf = gp[HIDDEN + j] + ag[1];
    const float gg = gp[2 * HIDDEN + j] + ag[2];
    const float go = gp[3 * HIDDEN + j] + ag[3];
    const float si = 1.0f / (1.0f + expf(-gi));
    const float sf = 1.0f / (1.0f + expf(-gf));
    const float tg = tanhf(gg);
    const float so = 1.0f / (1.0f + expf(-go));
    const float c2 = sf * cin[j] + si * tg;
    const float h2 = so * tanhf(c2);
    cout[j] = c2;
    hout[j] = h2;
  }
}

// B (fat): one dispatch, two roles by blockIdx.
//  bid <  NSB : bf16 screen of h(t+1) -> Lb + per-block packed max slot.
//  bid >= NSB : gp(t+1)[row] = bih+bhh + wihR[row]·emb[seq[t+1]] + whh[row]·h(t+1).
// All cross-kernel visibility via stream order (plain stores).
__global__ __launch_bounds__(256, 4)
void screen_gp(const u16* __restrict__ wb, const float* __restrict__ blin,
               const float* __restrict__ wih, const float* __restrict__ whh,
               const float* __restrict__ bih, const float* __restrict__ bhh,
               const float* __restrict__ emb, const int* __restrict__ seq,
               const float* __restrict__ hbufs, float* __restrict__ Lb,
               u64* __restrict__ partials, float* __restrict__ gp, int t) {
  __shared__ __align__(16) float xs2[EMBED];
  __shared__ __align__(16) float hs2[HIDDEN];
  __shared__ u64 red[4];
  const int tid = threadIdx.x;
  const int lane = tid & 63;
  const int wid = tid >> 6;
  const int bid = blockIdx.x;

  const float* h = hbufs + ((t + 1) & 1) * HIDDEN;

  if (bid < NSB) {
    // ---------------- screen role (identical numerics to round 5) --------
    const float4* h4p = (const float4*)h;
    const float4 ha0 = h4p[2 * lane];
    const float4 ha1 = h4p[2 * lane + 1];
    const float4 hb0 = h4p[2 * (lane + 64)];
    const float4 hb1 = h4p[2 * (lane + 64) + 1];

    const int row0 = bid * 32 + wid * 8;
    float acc[8];
    uint4 w0[4], w1[4];
    const uint4 z4 = make_uint4(0u, 0u, 0u, 0u);

#pragma unroll
    for (int r = 0; r < 4; ++r) {
      const int row = row0 + r;
      const uint4* wr = (const uint4*)(wb + (size_t)row * HIDDEN);
      const bool ok = row < VOCAB;
      w0[r] = ok ? wr[lane] : z4;
      w1[r] = ok ? wr[lane + 64] : z4;
    }
#pragma unroll
    for (int r = 0; r < 4; ++r)
      acc[r] = dot8(w0[r], ha0, ha1) + dot8(w1[r], hb0, hb1);

#pragma unroll
    for (int r = 0; r < 4; ++r) {
      const int row = row0 + 4 + r;
      const uint4* wr = (const uint4*)(wb + (size_t)row * HIDDEN);
      const bool ok = row < VOCAB;
      w0[r] = ok ? wr[lane] : z4;
      w1[r] = ok ? wr[lane + 64] : z4;
    }
#pragma unroll
    for (int r = 0; r < 4; ++r)
      acc[4 + r] = dot8(w0[r], ha0, ha1) + dot8(w1[r], hb0, hb1);

#pragma unroll
    for (int off = 32; off > 0; off >>= 1) {
#pragma unroll
      for (int r = 0; r < 8; ++r) acc[r] += __shfl_down(acc[r], off);
    }

    if (lane == 0) {
      u64 best = 0;
#pragma unroll
      for (int r = 0; r < 8; ++r) {
        const int row = row0 + r;
        if (row < VOCAB) {
          const float lg = acc[r] + blin[row];
          Lb[row] = lg;
          const u64 pk = ((u64)fmono(lg) << 32) | (u32)(VOCAB - row);
          if (pk > best) best = pk;
        }
      }
      red[wid] = best;
    }
    __syncthreads();
    if (tid == 0) {
      u64 m = red[0];
      if (red[1] > m) m = red[1];
      if (red[2] > m) m = red[2];
      if (red[3] > m) m = red[3];
      partials[(t & 1) * NSB + bid] = m;  // own slot, plain store
    }
  } else {
    // ---------------- gate-partial role: gp(t+1) --------------------------
    const int tok = seq[t + 1];
    for (int i = tid; i < EMBED; i += 256) xs2[i] = emb[(size_t)tok * EMBED + i];
    for (int i = tid; i < HIDDEN; i += 256) hs2[i] = h[i];
    __syncthreads();

    const int row = ((bid - NSB) << 2) + wid;  // 0..4095
    const float4* wr = (const float4*)(wih + (size_t)row * XDIM);
    const float4* hr = (const float4*)(whh + (size_t)row * HIDDEN);
    float a = 0.f;
#pragma unroll
    for (int i = 0; i < 2; ++i) {
      const int k = lane + i * 64;
      a += dotf4(wr[128 + k], *((const float4*)&xs2[k * 4]));  // cols 512..1023
    }
#pragma unroll
    for (int i = 0; i < 4; ++i) {
      const int k = lane + i * 64;
      a += dotf4(hr[k], *((const float4*)&hs2[k * 4]));
    }
    a = wave_reduce_sum(a);
    if (lane == 0) gp[row] = a + bih[row] + bhh[row];
  }
}

// exact fp32 logits of the final step -> d_out (identical dot to round 0)
__global__ __launch_bounds__(256)
void logits_out(const float* __restrict__ wlin, const float* __restrict__ blin,
                const float* __restrict__ h, float* __restrict__ out) {
  __shared__ __align__(16) float hs[HIDDEN];
  const int tid = threadIdx.x;
  const int lane = tid & 63;
  const int wid = tid >> 6;
  for (int i = tid; i < HIDDEN; i += 256) hs[i] = h[i];
  __syncthreads();
  const int row = blockIdx.x * 4 + wid;
  if (row < VOCAB) {
    const float4* wr = (const float4*)(wlin + (size_t)row * HIDDEN);
    float a = 0.f;
#pragma unroll
    for (int i = 0; i < 4; ++i) {
      const int k = lane + i * 64;
      a += dotf4(wr[k], *((const float4*)&hs[k * 4]));
    }
    a = wave_reduce_sum(a);
    if (lane == 0) out[row] = a + blin[row];
  }
}

// ====================== fallback (round-0) path ======================

__global__ void init_state_v0(const float* __restrict__ h0, const float* __restrict__ c0,
                              float* __restrict__ hbufs, float* __restrict__ cbufs,
                              u64* __restrict__ partials) {
  int i = threadIdx.x;
  if (i < HIDDEN) {
    hbufs[i] = h0[i];
    cbufs[i] = c0[i];
  }
  if (i < 512) partials[i] = 0ull;
}

__global__ __launch_bounds__(256)
void lstm_step_v0(const float* __restrict__ emb,
                  const float* __restrict__ wih, const float* __restrict__ whh,
                  const float* __restrict__ bih, const float* __restrict__ bhh,
                  const int* __restrict__ seq,
                  float* __restrict__ hbufs, float* __restrict__ cbufs,
                  u64* __restrict__ partials, int t) {
  __shared__ __align__(16) float xs[XDIM];
  __shared__ __align__(16) float hs[HIDDEN];
  __shared__ u64 red[4];
  __shared__ int ptok_s;

  const int tid = threadIdx.x;
  const int lane = tid & 63;
  const int wid = tid >> 6;

  const float* hin = hbufs + (t & 1) * HIDDEN;
  const float* cin = cbufs + (t & 1) * HIDDEN;
  float* hout = hbufs + ((t + 1) & 1) * HIDDEN;
  float* cout = cbufs + ((t + 1) & 1) * HIDDEN;

  int ptok = -1;
  if (t > 0) {
    const u64* part = partials + ((t + 1) & 1) * 256;
    u64 v = wave_reduce_max_u64(part[tid]);
    if (lane == 0) red[wid] = v;
    __syncthreads();
    if (tid == 0) {
      u64 m = red[0];
      if (red[1] > m) m = red[1];
      if (red[2] > m) m = red[2];
      if (red[3] > m) m = red[3];
      ptok_s = VOCAB - (int)(u32)(m & 0xFFFFFFFFu);
    }
    __syncthreads();
    ptok = ptok_s;
  }
  if (blockIdx.x == 0) partials[(t & 1) * 256 + tid] = 0ull;

  const int tok = seq[t];
  for (int i = tid; i < EMBED; i += 256) {
    xs[i] = (t == 0) ? 0.0f : emb[(size_t)ptok * EMBED + i];
    xs[EMBED + i] = emb[(size_t)tok * EMBED + i];
  }
  for (int i = tid; i < HIDDEN; i += 256) hs[i] = hin[i];
  __syncthreads();

  const int j = blockIdx.x * 4 + wid;
  float acc[4];
#pragma unroll
  for (int g = 0; g < 4; ++g) {
    const float4* wx = (const float4*)(wih + (size_t)(g * HIDDEN + j) * XDIM);
    const float4* wh = (const float4*)(whh + (size_t)(g * HIDDEN + j) * HIDDEN);
    float a = 0.f;
#pragma unroll
    for (int i = 0; i < 4; ++i) {
      const int k = lane + i * 64;
      a += dotf4(wx[k], *((const float4*)&xs[k * 4]));
      a += dotf4(wh[k], *((const float4*)&hs[k * 4]));
    }
    acc[g] = wave_reduce_sum(a);
  }

  if (lane == 0) {
    float gi = acc[0] + bih[j] + bhh[j];
    float gf = acc[1] + bih[HIDDEN + j] + bhh[HIDDEN + j];
    float gg = acc[2] + bih[2 * HIDDEN + j] + bhh[2 * HIDDEN + j];
    float go = acc[3] + bih[3 * HIDDEN + j] + bhh[3 * HIDDEN + j];
    float si = 1.0f / (1.0f + expf(-gi));
    float sf = 1.0f / (1.0f + expf(-gf));
    float tg = tanhf(gg);
    float so = 1.0f / (1.0f + expf(-go));
    float c2 = sf * cin[j] + si * tg;
    float h2 = so * tanhf(c2);
    cout[j] = c2;
    hout[j] = h2;
  }
}

__global__ __launch_bounds__(256)
void logits_step_v0(const float* __restrict__ wlin, const float* __restrict__ blin,
                    const float* __restrict__ hbufs, float* __restrict__ out,
                    u64* __restrict__ partials, int t) {
  __shared__ __align__(16) float hs[HIDDEN];
  __shared__ u64 red[4];
  const int tid = threadIdx.x;
  const int lane = tid & 63;
  const int wid = tid >> 6;

  const float* h = hbufs + ((t + 1) & 1) * HIDDEN;
  for (int i = tid; i < HIDDEN; i += 256) hs[i] = h[i];
  __syncthreads();

  const int row = blockIdx.x * 4 + wid;
  u64 pk = 0ull;
  if (row < VOCAB) {
    const float4* wr = (const float4*)(wlin + (size_t)row * HIDDEN);
    float a = 0.f;
#pragma unroll
    for (int i = 0; i < 4; ++i) {
      const int k = lane + i * 64;
      a += dotf4(wr[k], *((const float4*)&hs[k * 4]));
    }
    a = wave_reduce_sum(a);
    if (lane == 0) {
      float logit = a + blin[row];
      out[row] = logit;
      pk = ((u64)fmono(logit) << 32) | (u32)(VOCAB - row);
    }
  }
  if (lane == 0) red[wid] = pk;
  __syncthreads();
  if (tid == 0) {
    u64 m = red[0];
    if (red[1] > m) m = red[1];
    if (red[2] > m) m = red[2];
    if (red[3] > m) m = red[3];
    atomicMax(&partials[(t & 1) * 256 + (blockIdx.x & 255)], m);
  }
}

extern "C" void kernel_launch(void* const* d_in, const int* in_sizes, int n_in,
                              void* d_out, int out_size, void* d_ws, size_t ws_size,
                              hipStream_t stream) {
  const int* seq = (const int*)d_in[0];
  const float* h0 = (const float*)d_in[1];
  const float* c0 = (const float*)d_in[2];
  const float* emb = (const float*)d_in[3];
  const float* wih = (const float*)d_in[4];
  const float* whh = (const float*)d_in[5];
  const float* bih = (const float*)d_in[6];
  const float* bhh = (const float*)d_in[7];
  const float* wlin = (const float*)d_in[8];
  const float* blin = (const float*)d_in[9];
  float* out = (float*)d_out;

  // ws layout (aligned offsets)
  const size_t OFF_P = 0;                          // partials: 2*NSB u64 (25136)
  const size_t OFF_H = 25600;                      // hbufs: 2*1024 f
  const size_t OFF_C = OFF_H + 8192;               // cbufs: 2*1024 f
  const size_t OFF_GP = OFF_C + 8192;              // gp: 4096 f
  const size_t OFF_LB = OFF_GP + 16384;            // Lb: VOCAB f (pad)
  const size_t OFF_WB = OFF_LB + 201216;           // wb: VOCAB*HIDDEN bf16
  const size_t NEED = OFF_WB + (size_t)VOCAB * HIDDEN * 2;

  u64* partials = (u64*)((char*)d_ws + OFF_P);
  float* hbufs = (float*)((char*)d_ws + OFF_H);
  float* cbufs = (float*)((char*)d_ws + OFF_C);
  float* gp = (float*)((char*)d_ws + OFF_GP);
  float* Lb = (float*)((char*)d_ws + OFF_LB);
  u16* wb = (u16*)((char*)d_ws + OFF_WB);

  if (ws_size >= NEED) {
    init_state<<<1, 1024, 0, stream>>>(h0, c0, hbufs, cbufs);
    const long long n8 = (long long)VOCAB * HIDDEN / 8;
    convert_wlin<<<(int)((n8 + 255) / 256), 256, 0, stream>>>(wlin, wb);
    gates_init<<<NGB, 256, 0, stream>>>(wih, whh, bih, bhh, emb, seq, hbufs, gp);
    for (int t = 0; t < SEQLEN; ++t) {
      lstm_thin<<<HIDDEN / 4, 256, 0, stream>>>(emb, wih, wlin, blin, gp,
                                                hbufs, cbufs, partials, Lb, t);
      if (t < SEQLEN - 1)
        screen_gp<<<NSB + NGB, 256, 0, stream>>>(wb, blin, wih, whh, bih, bhh,
                                                 emb, seq, hbufs, Lb, partials,
                                                 gp, t);
    }
    // h(512) lives at parity (512)&1 == 0
    logits_out<<<(VOCAB + 3) / 4, 256, 0, stream>>>(wlin, blin, hbufs, out);
  } else {
    // fallback: round-0 fp32 path (known-correct)
    u64* p0 = (u64*)d_ws;
    float* hb0 = (float*)((char*)d_ws + 4096);
    float* cb0 = hb0 + 2 * HIDDEN;
    init_state_v0<<<1, 1024, 0, stream>>>(h0, c0, hb0, cb0, p0);
    for (int t = 0; t < SEQLEN; ++t) {
      lstm_step_v0<<<HIDDEN / 4, 256, 0, stream>>>(emb, wih, whh, bih, bhh, seq,
                                                   hb0, cb0, p0, t);
      logits_step_v0<<<(VOCAB + 3) / 4, 256, 0, stream>>>(wlin, blin, hb0, out,
                                                          p0, t);
    }
  }
}